// Round 9
// baseline (384.597 us; speedup 1.0000x reference)
//
#include <hip/hip_runtime.h>
#include <cstddef>

#define NTOK 2048
#define BDIM 4
#define DIM 256
#define NHEAD 4
#define MROWS 8192
#define M2 16384                        // both descriptors batched
#define NMu ((size_t)MROWS * DIM)       // 2,097,152 elems (bf16 unit = 4 MB)

typedef unsigned short u16;
typedef __attribute__((ext_vector_type(8))) short short8;
typedef __attribute__((ext_vector_type(4))) float f32x4;
typedef __attribute__((ext_vector_type(16))) float f32x16;

#if __has_builtin(__builtin_amdgcn_exp2f)
#define EXP2(x) __builtin_amdgcn_exp2f(x)
#else
#define EXP2(x) exp2f(x)
#endif

__device__ __forceinline__ u16 f2bf(float x) {
  union { float f; unsigned u; } c; c.f = x;
  unsigned r = c.u + 0x7FFFu + ((c.u >> 16) & 1u);
  return (u16)(r >> 16);
}
__device__ __forceinline__ float bf2f(u16 u) {
  union { unsigned u; float f; } c; c.u = ((unsigned)u) << 16;
  return c.f;
}
// packed f32->bf16 (RNE), dst = {bf16(lo), bf16(hi)} (T12 recipe; no builtin)
__device__ __forceinline__ unsigned cvtpk(float lo, float hi) {
  unsigned r;
  asm("v_cvt_pk_bf16_f32 %0, %1, %2" : "=v"(r) : "v"(lo), "v"(hi));
  return r;
}

__device__ __forceinline__ void glds16(const void* g, void* l) {
  __builtin_amdgcn_global_load_lds(
      (const __attribute__((address_space(1))) unsigned int*)g,
      (__attribute__((address_space(3))) unsigned int*)l, 16, 0, 0);
}

// ---------------------------------------------------------------------------
// bf16 MFMA GEMM, 128x128 tile, BK=64 as two stacked BK=32 LDS panels
// (round-2 winner, verbatim). Y = (A @ W^T + bias)*oscale; A split at
// kSplit; N split at nsplit.
// ---------------------------------------------------------------------------
__global__ __launch_bounds__(256) void gemm_bf16_kernel(
    const u16* __restrict__ A, int lda,
    const u16* __restrict__ A2, int lda2, int kSplit,
    const u16* __restrict__ W,
    const float* __restrict__ bias0, const float* __restrict__ bias1,
    int nsplit, float os0, float os1,
    u16* __restrict__ Yb0, int ldy0,
    u16* __restrict__ Yb1, int ldy1,
    int K)
{
  __shared__ u16 As[2 * 4096];   // [kh][row][32]
  __shared__ u16 Bs[2 * 4096];
  const int t = threadIdx.x;
  const int m0 = blockIdx.y * 128, n0 = blockIdx.x * 128;
  const int r4 = t >> 2, c8 = (t & 3) * 8;
  const int lane = t & 63, w = t >> 6;
  const int cl = lane & 15, quad = lane >> 4;
  const int wm = (w >> 1) * 64, wn = (w & 1) * 64;

  f32x4 acc[4][4];
#pragma unroll
  for (int i = 0; i < 4; ++i)
#pragma unroll
    for (int j = 0; j < 4; ++j) acc[i][j] = (f32x4){0.f, 0.f, 0.f, 0.f};

  for (int k0 = 0; k0 < K; k0 += 64) {
    const u16* Ab; int la; int kk;
    if (k0 < kSplit) { Ab = A; la = lda; kk = k0; }
    else             { Ab = A2; la = lda2; kk = k0 - kSplit; }
    const u16* ag = Ab + (size_t)(m0 + r4) * la + kk + c8;
    const u16* bg = W + (size_t)(n0 + r4) * K + k0 + c8;
    __syncthreads();
#pragma unroll
    for (int kh = 0; kh < 2; ++kh) {
      glds16(ag + kh * 32, &As[kh * 4096 + t * 8]);
      glds16(ag + (size_t)64 * la + kh * 32, &As[kh * 4096 + 2048 + t * 8]);
      glds16(bg + kh * 32, &Bs[kh * 4096 + t * 8]);
      glds16(bg + (size_t)64 * K + kh * 32, &Bs[kh * 4096 + 2048 + t * 8]);
    }
    __syncthreads();

#pragma unroll
    for (int kh = 0; kh < 2; ++kh) {
      short8 af[4], bfr[4];
#pragma unroll
      for (int i = 0; i < 4; ++i)
        af[i] = *(const short8*)&As[kh * 4096 + (wm + i * 16 + cl) * 32 + quad * 8];
#pragma unroll
      for (int i = 0; i < 4; ++i)
        bfr[i] = *(const short8*)&Bs[kh * 4096 + (wn + i * 16 + cl) * 32 + quad * 8];
#pragma unroll
      for (int mt = 0; mt < 4; ++mt)
#pragma unroll
        for (int nt = 0; nt < 4; ++nt)
          acc[mt][nt] = __builtin_amdgcn_mfma_f32_16x16x32_bf16(
              af[mt], bfr[nt], acc[mt][nt], 0, 0, 0);
    }
  }

#pragma unroll
  for (int mt = 0; mt < 4; ++mt)
#pragma unroll
    for (int nt = 0; nt < 4; ++nt) {
      const int colg = n0 + wn + nt * 16 + cl;
      const bool first = colg < nsplit;
      const int c2 = first ? colg : colg - nsplit;
      const float bs = first ? bias0[c2] : bias1[c2];
      const float os = first ? os0 : os1;
      u16* yb = first ? Yb0 : Yb1;
      const int ly = first ? ldy0 : ldy1;
#pragma unroll
      for (int r = 0; r < 4; ++r) {
        const int rowg = m0 + wm + mt * 16 + quad * 4 + r;
        yb[(size_t)rowg * ly + c2] = f2bf((acc[mt][nt][r] + bs) * os);
      }
    }
}

// ---------------------------------------------------------------------------
// bf16 MFMA GEMM, 64x64 tile, BK=64 (round-2 winner, verbatim).
// ---------------------------------------------------------------------------
__global__ __launch_bounds__(256) void gemm64_kernel(
    const u16* __restrict__ A, int lda,
    const u16* __restrict__ W,
    const float* __restrict__ bias,
    const u16* __restrict__ resb, int ldrb,
    float* __restrict__ Yf, int ldyf,
    u16* __restrict__ Yb, int ldyb,
    int K)
{
  __shared__ u16 As[2 * 2048];
  __shared__ u16 Bs[2 * 2048];
  const int t = threadIdx.x;
  const int m0 = blockIdx.y * 64, n0 = blockIdx.x * 64;
  const int r8 = t >> 2, c8 = (t & 3) * 8;
  const int lane = t & 63, w = t >> 6;
  const int cl = lane & 15, quad = lane >> 4;
  const int wm = (w >> 1) * 32, wn = (w & 1) * 32;

  f32x4 acc[2][2];
#pragma unroll
  for (int i = 0; i < 2; ++i)
#pragma unroll
    for (int j = 0; j < 2; ++j) acc[i][j] = (f32x4){0.f, 0.f, 0.f, 0.f};

  for (int k0 = 0; k0 < K; k0 += 64) {
    const u16* ag = A + (size_t)(m0 + r8) * lda + k0 + c8;
    const u16* bg = W + (size_t)(n0 + r8) * K + k0 + c8;
    __syncthreads();
#pragma unroll
    for (int kh = 0; kh < 2; ++kh) {
      glds16(ag + kh * 32, &As[kh * 2048 + t * 8]);
      glds16(bg + kh * 32, &Bs[kh * 2048 + t * 8]);
    }
    __syncthreads();

#pragma unroll
    for (int kh = 0; kh < 2; ++kh) {
      short8 af[2], bfr[2];
#pragma unroll
      for (int i = 0; i < 2; ++i)
        af[i] = *(const short8*)&As[kh * 2048 + (wm + i * 16 + cl) * 32 + quad * 8];
#pragma unroll
      for (int j = 0; j < 2; ++j)
        bfr[j] = *(const short8*)&Bs[kh * 2048 + (wn + j * 16 + cl) * 32 + quad * 8];
#pragma unroll
      for (int mt = 0; mt < 2; ++mt)
#pragma unroll
        for (int nt = 0; nt < 2; ++nt)
          acc[mt][nt] = __builtin_amdgcn_mfma_f32_16x16x32_bf16(
              af[mt], bfr[nt], acc[mt][nt], 0, 0, 0);
    }
  }

#pragma unroll
  for (int mt = 0; mt < 2; ++mt)
#pragma unroll
    for (int nt = 0; nt < 2; ++nt) {
      const int colg = n0 + wn + nt * 16 + cl;
      const float bs = bias[colg];
#pragma unroll
      for (int r = 0; r < 4; ++r) {
        const int rowg = m0 + wm + mt * 16 + quad * 4 + r;
        float v = acc[mt][nt][r] + bs;
        if (resb) v += bf2f(resb[(size_t)rowg * ldrb + colg]);
        if (Yf) Yf[(size_t)rowg * ldyf + colg] = v;
        if (Yb) Yb[(size_t)rowg * ldyb + colg] = f2bf(v);
      }
    }
}

// ---------------------------------------------------------------------------
// FUSED pack + wfuse (independent data -> run concurrently, saves a launch).
// ---------------------------------------------------------------------------
__global__ __launch_bounds__(256) void pack_wfuse_kernel(
    const float* w0, const float* w1, const float* w2, const float* w3,
    const float* w4, const float* d0, const float* d1,
    u16* __restrict__ wb, u16* __restrict__ descb,
    const float* __restrict__ W1, const float* __restrict__ Wo,
    const float* __restrict__ b1, const float* __restrict__ bo,
    const float* __restrict__ cW1, const float* __restrict__ cWo,
    const float* __restrict__ cb1, const float* __restrict__ cbo,
    u16* __restrict__ W1f, u16* __restrict__ cW1f,
    float* __restrict__ b1f, float* __restrict__ cb1f)
{
  __shared__ float rowh[256];
  const int bid = blockIdx.x;
  const int t = threadIdx.x;
  if (bid < 4672) {
    const size_t idx4 = ((size_t)bid * 256 + t) * 4;
    const float* src; u16* dst; size_t off;
    if (idx4 < 589824) {
      off = idx4; dst = wb + idx4;
      if      (idx4 < 196608) { src = w0; }
      else if (idx4 < 327680) { src = w1; off -= 196608; }
      else if (idx4 < 393216) { src = w2; off -= 327680; }
      else if (idx4 < 458752) { src = w3; off -= 393216; }
      else                    { src = w4; off -= 458752; }
    } else {
      size_t o = idx4 - 589824;
      dst = descb + o;
      if (o < NMu) { src = d0; off = o; }
      else         { src = d1; off = o - NMu; }
    }
    float4 v = *(const float4*)(src + off);
    ushort4 ov;
    ov.x = f2bf(v.x); ov.y = f2bf(v.y); ov.z = f2bf(v.z); ov.w = f2bf(v.w);
    *(ushort4*)dst = ov;
  } else {
    const int idx = bid - 4672;
    const int n = idx & 511, sel = idx >> 9;
    const float* Ws = sel ? cW1 : W1;
    const float* Wos = sel ? cWo : Wo;
    u16* out = sel ? cW1f : W1f;
    rowh[t] = Ws[(size_t)n * 512 + 256 + t];
    out[(size_t)n * 512 + t] = f2bf(Ws[(size_t)n * 512 + t]);
    __syncthreads();
    float acc = 0.f;
    for (int m = 0; m < 256; ++m) acc += rowh[m] * Wos[(size_t)m * 256 + t];
    out[(size_t)n * 512 + 256 + t] = f2bf(acc);
    if (t == 0) {
      const float* bos = sel ? cbo : bo;
      const float* b1s = sel ? cb1 : b1;
      float a = b1s[n];
      for (int m = 0; m < 256; ++m) a += rowh[m] * bos[m];
      (sel ? cb1f : b1f)[n] = a;
    }
  }
}

// ---------------------------------------------------------------------------
// FUSED RoPE + V-transpose (round-8). Writes Q, K, Vt directly.
// ---------------------------------------------------------------------------
__global__ __launch_bounds__(256) void rope_tv_kernel(
    const u16* __restrict__ qkv, const float* __restrict__ enc0,
    const float* __restrict__ enc1,
    u16* __restrict__ Q, u16* __restrict__ K, u16* __restrict__ Vt)
{
  __shared__ u16 Vl[64 * 264];        // [tok][256 d + 8 pad]
  const int blk = blockIdx.x;         // 0..255 (64-token slabs over M2)
  const int t = threadIdx.x;
  const int hf = blk >> 7;            // descriptor half (slab-uniform)
  const float* enc = hf ? enc1 : enc0;
  const float QSC = 0.18033688011112042f;   // 0.125 * log2(e) -> exp2 softmax

  for (int p = 0; p < 32; ++p) {
    const int j = p * 256 + t;        // 0..8191 task id
    const int i = j & 31;
    const int h = (j >> 5) & 3;
    const int lt = j >> 7;            // 0..63 token-in-slab
    const int m = blk * 64 + lt;
    const int lm = m & (MROWS - 1);
    const u16* src = qkv + (size_t)m * 768 + h * 192 + i * 6;
    const unsigned a0 = *(const unsigned*)(src);
    const unsigned a1 = *(const unsigned*)(src + 2);
    const unsigned a2 = *(const unsigned*)(src + 4);
    const float q0 = bf2f((u16)a0), k0 = bf2f((u16)(a0 >> 16));
    const float v0 = bf2f((u16)a1), q1 = bf2f((u16)(a1 >> 16));
    const float k1 = bf2f((u16)a2), v1 = bf2f((u16)(a2 >> 16));
    const float c = enc[(size_t)lm * 64 + 2 * i];
    const float s = enc[(size_t)MROWS * 64 + (size_t)lm * 64 + 2 * i];
    const size_t o = (size_t)m * 256 + h * 64 + 2 * i;
    *(unsigned*)(Q + o) = (unsigned)f2bf((q0 * c - q1 * s) * QSC) |
                          ((unsigned)f2bf((q1 * c + q0 * s) * QSC) << 16);
    *(unsigned*)(K + o) = (unsigned)f2bf(k0 * c - k1 * s) |
                          ((unsigned)f2bf(k1 * c + k0 * s) << 16);
    *(unsigned*)&Vl[lt * 264 + h * 64 + 2 * i] =
        (unsigned)f2bf(v0) | ((unsigned)f2bf(v1) << 16);
  }
  __syncthreads();

  const int bz = blk >> 5, n0 = (blk & 31) * 64;
  const int dd = t >> 2, qr = t & 3;
#pragma unroll
  for (int h = 0; h < 4; ++h) {
    union { u16 u[16]; uint4 v[2]; } pk;
#pragma unroll
    for (int jj = 0; jj < 16; ++jj)
      pk.u[jj] = Vl[(qr * 16 + jj) * 264 + h * 64 + dd];
    u16* dst = Vt + ((size_t)((bz * NHEAD + h) * 64 + dd)) * NTOK + n0 + qr * 16;
    *(uint4*)dst = pk.v[0];
    *(uint4*)(dst + 8) = pk.v[1];
  }
}

// bf16 unheads (M2,256) -> bf16 transposed head-major (8,H,64,2048)
// (retained for the cross block's V)
__global__ __launch_bounds__(256) void transpose_v_kernel(
    const u16* __restrict__ in, u16* __restrict__ out)
{
  __shared__ u16 Tl[64][72];
  const int bz = blockIdx.z, h = blockIdx.y;
  const int n0 = blockIdx.x * 64;
  const int t = threadIdx.x;
  {
    const int row = t >> 2, c16 = (t & 3) * 16;
    const u16* src = in + (size_t)(bz * NTOK + n0 + row) * 256 + h * 64 + c16;
    *(uint4*)&Tl[row][c16] = *(const uint4*)src;
    *(uint4*)&Tl[row][c16 + 8] = *(const uint4*)(src + 8);
  }
  __syncthreads();
  const int d = t >> 2, qr = t & 3;
  union { u16 u[16]; uint4 v[2]; } pk;
#pragma unroll
  for (int j = 0; j < 16; ++j) pk.u[j] = Tl[qr * 16 + j][d];
  u16* dst = out + ((size_t)((bz * NHEAD + h) * 64 + d)) * NTOK + n0 + qr * 16;
  *(uint4*)dst = pk.v[0];
  *(uint4*)(dst + 8) = pk.v[1];
}

// ---------------------------------------------------------------------------
// MFMA flash attention v9: 32x32 SWAPPED-OPERAND structure (m214-style).
// S = mfma_32x32x16(K, Q): C col=lane&31 -> each lane holds S for ONE q
// (32 key values in regs) => softmax is lane-local: 32 exp2, in-lane sum,
// ONE shfl_xor(32). P->PV A-fragments built IN REGISTERS via
// v_cvt_pk_bf16_f32 (16) + shfl_xor(32) (16) + cndmask selects -- NO P LDS
// round-trip (was the remaining serial dependency + all 2.1M conflicts).
// Keeps: swizzled pitch-64 K/V LDS double-buffer, 1 barrier/tile,
// direct-global Q, setprio, XCD-grouped decode, max-free exp2 softmax.
// LDS 32 KB; grid 512 = 2 blocks/CU; 8 MFMA+8 LDS-reads per QK (was 16+8).
// ---------------------------------------------------------------------------
__global__ __launch_bounds__(256, 2) void attn9_kernel(
    const u16* __restrict__ Qb, const u16* __restrict__ Kb,
    const u16* __restrict__ Vtb, u16* __restrict__ Ou, int cross)
{
  __shared__ u16 Ks[2][64 * 64];
  __shared__ u16 Vs[2][64 * 64];

  const int hw = blockIdx.x;          // 0..511
  const int li = hw >> 3;             // 0..63 within XCD
  const int y  = (hw & 7) * 4 + (li >> 4);   // 0..31
  const int n0 = (li & 15) * 128;

  const int h2 = y >> 4, b = (y >> 2) & 3, h = y & 3;
  const int kh = cross ? (1 - h2) : h2;
  const int qrowbase = (h2 * 4 + b) * NTOK;
  const int krowbase = (kh * 4 + b) * NTOK;
  const int vz = kh * 4 + b;
  const int t = threadIdx.x, lane = t & 63, w = t >> 6;
  const int l31 = lane & 31, hi = lane >> 5;
  const int q0 = w * 32;
  const int fsw = (l31 & 7) << 4;     // read swizzle (row&7 == l31&7)

  // Q fragments (B-operand of mfma(K,Q)): col=q=l31, k=d=ks*16+hi*8+e
  short8 bq[4];
  {
    const u16* qsrc = Qb + (size_t)(qrowbase + n0 + q0 + l31) * 256 +
                      h * 64 + hi * 8;
#pragma unroll
    for (int ks = 0; ks < 4; ++ks) bq[ks] = *(const short8*)(qsrc + ks * 16);
  }

  float l_r = 0.f;
  f32x16 o0, o1;
#pragma unroll
  for (int i = 0; i < 16; ++i) { o0[i] = 0.f; o1[i] = 0.f; }

  const int srow = t >> 2;            // 0..63 staging row
  const int scb = (t & 3) * 32;       // staging byte col (2 x 16B per thread)
  const int ssw = (srow & 7) << 4;    // staging swizzle
  const u16* Kg = Kb + (size_t)(krowbase + srow) * 256 + h * 64 + (t & 3) * 16;
  const u16* Vg = Vtb + ((size_t)(vz * NHEAD + h) * 64 + srow) * NTOK + (t & 3) * 16;

  // prologue: tile0 -> buf0, prefetch tile1 into regs
  uint4 ka0 = *(const uint4*)Kg, ka1 = *(const uint4*)(Kg + 8);
  uint4 va0 = *(const uint4*)Vg, va1 = *(const uint4*)(Vg + 8);
  {
    char* kd = (char*)&Ks[0][srow * 64];
    *(uint4*)(kd + (scb ^ ssw)) = ka0;
    *(uint4*)(kd + ((scb + 16) ^ ssw)) = ka1;
    char* vd = (char*)&Vs[0][srow * 64];
    *(uint4*)(vd + (scb ^ ssw)) = va0;
    *(uint4*)(vd + ((scb + 16) ^ ssw)) = va1;
  }
  Kg += 64 * 256; Vg += 64;
  ka0 = *(const uint4*)Kg; ka1 = *(const uint4*)(Kg + 8);
  va0 = *(const uint4*)Vg; va1 = *(const uint4*)(Vg + 8);
  __syncthreads();

  for (int tile = 0; tile < 32; ++tile) {
    const int cur = tile & 1, nxt = cur ^ 1;

    // QK^T: S(64 keys x 32 q); A=K rows (keys), accumulate over d (4 ksteps)
    f32x16 s0, s1;
#pragma unroll
    for (int i = 0; i < 16; ++i) { s0[i] = 0.f; s1[i] = 0.f; }
    __builtin_amdgcn_s_setprio(1);
#pragma unroll
    for (int ks = 0; ks < 4; ++ks) {
      const int ofs = (ks * 32 + hi * 16) ^ fsw;
      short8 ak0 = *(const short8*)((const char*)&Ks[cur][l31 * 64] + ofs);
      short8 ak1 = *(const short8*)((const char*)&Ks[cur][(32 + l31) * 64] + ofs);
      s0 = __builtin_amdgcn_mfma_f32_32x32x16_bf16(ak0, bq[ks], s0, 0, 0, 0);
      s1 = __builtin_amdgcn_mfma_f32_32x32x16_bf16(ak1, bq[ks], s1, 0, 0, 0);
    }
    __builtin_amdgcn_s_setprio(0);

    // stage next K into the other buffer, then prefetch the following K
    if (tile < 31) {
      char* kd = (char*)&Ks[nxt][srow * 64];
      *(uint4*)(kd + (scb ^ ssw)) = ka0;
      *(uint4*)(kd + ((scb + 16) ^ ssw)) = ka1;
      if (tile < 30) {
        Kg += 64 * 256;
        ka0 = *(const uint4*)Kg; ka1 = *(const uint4*)(Kg + 8);
      }
    }

    float rs = 0.f;
    // ---- per 32-key group: exp2 (lane-local row), in-register P repack,
    //      immediately consumed by PV over that key group ----
#pragma unroll
    for (int kg = 0; kg < 2; ++kg) {
      float p[16];
#pragma unroll
      for (int r = 0; r < 16; ++r) {
        p[r] = EXP2(kg ? s1[r] : s0[r]);
        rs += p[r];
      }
      // pack adjacent keys: lane holds keys j=(r&3)+8*(r>>2)+4*hi
      // pa4[g]={keys 8g+4hi, +1}, pb4[g]={+2,+3}; partner half via xor32.
      unsigned pa4[4], pb4[4], xa4[4], xb4[4];
#pragma unroll
      for (int g = 0; g < 4; ++g) {
        pa4[g] = cvtpk(p[4 * g], p[4 * g + 1]);
        pb4[g] = cvtpk(p[4 * g + 2], p[4 * g + 3]);
        xa4[g] = (unsigned)__shfl_xor((int)pa4[g], 32);
        xb4[g] = (unsigned)__shfl_xor((int)pb4[g], 32);
      }
      __builtin_amdgcn_s_setprio(1);
#pragma unroll
      for (int k2 = 0; k2 < 2; ++k2) {         // kstep within group
        const int g0 = (2 * k2) & 3, g1 = (2 * k2 + 1) & 3;
        union { unsigned u[4]; short8 s; } pa;
        pa.u[0] = hi ? xa4[g1] : pa4[g0];
        pa.u[1] = hi ? xb4[g1] : pb4[g0];
        pa.u[2] = hi ? pa4[g1] : xa4[g0];
        pa.u[3] = hi ? pb4[g1] : xb4[g0];
        const int ks = kg * 2 + k2;
        const int ofs = (ks * 32 + hi * 16) ^ fsw;
        short8 bv0 = *(const short8*)((const char*)&Vs[cur][l31 * 64] + ofs);
        short8 bv1 = *(const short8*)((const char*)&Vs[cur][(32 + l31) * 64] + ofs);
        o0 = __builtin_amdgcn_mfma_f32_32x32x16_bf16(pa.s, bv0, o0, 0, 0, 0);
        o1 = __builtin_amdgcn_mfma_f32_32x32x16_bf16(pa.s, bv1, o1, 0, 0, 0);
      }
      __builtin_amdgcn_s_setprio(0);
    }
    l_r += rs + __shfl_xor(rs, 32);   // full row sum for q=l31

    // stage next V, prefetch following V
    if (tile < 31) {
      char* vd = (char*)&Vs[nxt][srow * 64];
      *(uint4*)(vd + (scb ^ ssw)) = va0;
      *(uint4*)(vd + ((scb + 16) ^ ssw)) = va1;
      if (tile < 30) {
        Vg += 64;
        va0 = *(const uint4*)Vg; va1 = *(const uint4*)(Vg + 8);
      }
    }
    __syncthreads();   // single barrier per tile
  }

  // normalize and write bf16 ctx. O rows = q: qrow=(r&3)+8*(r>>2)+4*hi;
  // cols = d = dg*32+l31 (32-lane groups write 64B runs -> coalesced).
#pragma unroll
  for (int r = 0; r < 16; ++r) {
    const int qrow = (r & 3) + 8 * (r >> 2) + 4 * hi;
    const float lq = __shfl(l_r, qrow);
    const float inv = 1.f / lq;
    const size_t rowo = (size_t)(qrowbase + n0 + q0 + qrow) * 256 + h * 64;
    Ou[rowo + l31]      = f2bf(o0[r] * inv);
    Ou[rowo + 32 + l31] = f2bf(o1[r] * inv);
  }
}

// ---------------------------------------------------------------------------
// LayerNorm + exact GELU, bf16 in (M2,512) -> bf16 out
// ---------------------------------------------------------------------------
__global__ __launch_bounds__(256) void ln_gelu_kernel(
    const u16* __restrict__ Hm, const float* __restrict__ g,
    const float* __restrict__ be, u16* __restrict__ out)
{
  const int rowi = blockIdx.x * 4 + (threadIdx.x >> 6);
  const int lane = threadIdx.x & 63;
  const u16* row = Hm + (size_t)rowi * 512 + lane * 8;
  u16* orow = out + (size_t)rowi * 512 + lane * 8;
  uint4 raw = *(const uint4*)row;
  float x[8];
  const unsigned* rw = (const unsigned*)&raw;
#pragma unroll
  for (int i = 0; i < 4; ++i) {
    x[2 * i]     = bf2f((u16)rw[i]);
    x[2 * i + 1] = bf2f((u16)(rw[i] >> 16));
  }
  float s = 0.f;
#pragma unroll
  for (int i = 0; i < 8; ++i) s += x[i];
#pragma unroll
  for (int off = 32; off; off >>= 1) s += __shfl_xor(s, off);
  const float mean = s * (1.f / 512.f);
  float s2 = 0.f;
#pragma unroll
  for (int i = 0; i < 8; ++i) { const float d = x[i] - mean; s2 += d * d; }
#pragma unroll
  for (int off = 32; off; off >>= 1) s2 += __shfl_xor(s2, off);
  const float rstd = rsqrtf(s2 * (1.f / 512.f) + 1e-5f);
  unsigned ov[4];
#pragma unroll
  for (int i = 0; i < 4; ++i) {
    const int c = lane * 8 + 2 * i;
    const float y0 = (x[2 * i] - mean) * rstd * g[c] + be[c];
    const float y1 = (x[2 * i + 1] - mean) * rstd * g[c + 1] + be[c + 1];
    const float g0 = 0.5f * y0 * (1.f + erff(y0 * 0.70710678118654752f));
    const float g1 = 0.5f * y1 * (1.f + erff(y1 * 0.70710678118654752f));
    ov[i] = (unsigned)f2bf(g0) | ((unsigned)f2bf(g1) << 16);
  }
  *(uint4*)orow = *(uint4*)ov;
}

// ---------------------------------------------------------------------------
extern "C" void kernel_launch(void* const* d_in, const int* in_sizes, int n_in,
                              void* d_out, int out_size, void* d_ws, size_t ws_size,
                              hipStream_t stream) {
  const float* desc0  = (const float*)d_in[0];
  const float* desc1  = (const float*)d_in[1];
  const float* enc0   = (const float*)d_in[2];
  const float* enc1   = (const float*)d_in[3];
  const float* s_Wqkv = (const float*)d_in[4];
  const float* s_bqkv = (const float*)d_in[5];
  const float* s_Wout = (const float*)d_in[6];
  const float* s_bout = (const float*)d_in[7];
  const float* s_W1   = (const float*)d_in[8];
  const float* s_b1   = (const float*)d_in[9];
  const float* s_g    = (const float*)d_in[10];
  const float* s_be   = (const float*)d_in[11];
  const float* s_W2   = (const float*)d_in[12];
  const float* s_b2   = (const float*)d_in[13];
  const float* c_Wqk  = (const float*)d_in[14];
  const float* c_bqk  = (const float*)d_in[15];
  const float* c_Wv   = (const float*)d_in[16];
  const float* c_bv   = (const float*)d_in[17];
  const float* c_Wo   = (const float*)d_in[18];
  const float* c_bo   = (const float*)d_in[19];
  const float* c_W1   = (const float*)d_in[20];
  const float* c_b1   = (const float*)d_in[21];
  const float* c_g    = (const float*)d_in[22];
  const float* c_be   = (const float*)d_in[23];
  const float* c_W2   = (const float*)d_in[24];
  const float* c_b2   = (const float*)d_in[25];

  u16* U = (u16*)d_ws;
  u16* descb = U + 0 * NMu;             // [all]
  u16* qkvb  = U + 2 * NMu;             // 6u, phase A only
  u16* ctxb  = U + 2 * NMu;             // 2u, attn ctx out (self / cross)
  u16* Qu    = U + 8 * NMu;             // self Q / cross qkb
  u16* Ku    = U + 10 * NMu;            // self K / cross vb
  u16* Vt    = U + 14 * NMu;            // transposed V
  u16* hbufb = U + 12 * NMu;            // 4u ffn hidden (after attn)
  u16* hb2   = U + 16 * NMu;            // 4u ln out
  float* b1f = (float*)(U + 20 * NMu);  // 512 fp32
  float* cb1f = b1f + 512;
  u16* s_b   = U + 21 * NMu;            // self outputs
  u16* wb    = U + 23 * NMu;

  u16* Wqkvb = wb;                      // 196608
  u16* W2b   = wb + 196608;             // 131072
  u16* cQKVb = wb + 327680;             // cWqk(65536) || cWv(65536)
  u16* cW2b  = wb + 458752;             // 131072
  u16* W1f   = wb + 589824;             // 262144 (fused self FFN1 weight)
  u16* cW1f  = wb + 851968;             // 262144

  float* outf = (float*)d_out;

  const dim3 tv_grid(NTOK / 64, NHEAD, 8);
  const int lng_blocks  = M2 / 4;
  const float csc = 0.42466090014400953f;  // 8^-0.5 * sqrt(log2 e)

  // 1. pack weights + descs || wfuse (fused, concurrent)
  hipLaunchKernelGGL(pack_wfuse_kernel, dim3(5696), dim3(256), 0, stream,
                     s_Wqkv, s_W2, c_Wqk, c_Wv, c_W2, desc0, desc1, wb, descb,
                     s_W1, s_Wout, s_b1, s_bout, c_W1, c_Wo, c_b1, c_bo,
                     W1f, cW1f, b1f, cb1f);

  // ---------------- self blocks (batched) ----------------
  // 2. qkv GEMM
  hipLaunchKernelGGL(gemm_bf16_kernel, dim3(6, 128), dim3(256), 0, stream,
                     descb, 256, (const u16*)nullptr, 0, 1 << 30, Wqkvb,
                     s_bqkv, (const float*)nullptr, 1 << 30, 1.f, 1.f,
                     qkvb, 768, (u16*)nullptr, 0, 256);
  // 3. rope + V-transpose (fused; writes Qu, Ku, Vt directly)
  hipLaunchKernelGGL(rope_tv_kernel, dim3(256), dim3(256), 0, stream,
                     qkvb, enc0, enc1, Qu, Ku, Vt);
  // 4. attention (writes ctx directly)
  hipLaunchKernelGGL(attn9_kernel, dim3(512), dim3(256), 0, stream,
                     Qu, Ku, Vt, ctxb, 0);
  // 5. FFN1 (fused Wout): A=[descb | ctxb] @ W1f^T + b1f
  hipLaunchKernelGGL(gemm_bf16_kernel, dim3(4, 128), dim3(256), 0, stream,
                     descb, 256, ctxb, 256, 256, W1f,
                     b1f, (const float*)nullptr, 1 << 30, 1.f, 1.f,
                     hbufb, 512, (u16*)nullptr, 0, 512);
  // 6. LN + GELU
  hipLaunchKernelGGL(ln_gelu_kernel, dim3(lng_blocks), dim3(256), 0, stream,
                     hbufb, s_g, s_be, hb2);
  // 7. W2 + residual
  hipLaunchKernelGGL(gemm64_kernel, dim3(4, 256), dim3(256), 0, stream,
                     hb2, 512, W2b, s_b2, descb, 256,
                     (float*)nullptr, 0, s_b, 256, 512);

  // ---------------- cross block (batched) ----------------
  u16* qkb = Qu;
  u16* vb  = Ku;
  // 8. fused qk|v projection (per-half bias/scale/output)
  hipLaunchKernelGGL(gemm_bf16_kernel, dim3(4, 128), dim3(256), 0, stream,
                     s_b, 256, (const u16*)nullptr, 0, 1 << 30, cQKVb,
                     c_bqk, c_bv, 256, csc, 1.f,
                     qkb, 256, vb, 256, 256);
  // 9. transpose V
  hipLaunchKernelGGL(transpose_v_kernel, tv_grid, dim3(256), 0, stream, vb, Vt);
  // 10. attention (writes ctx directly)
  hipLaunchKernelGGL(attn9_kernel, dim3(512), dim3(256), 0, stream,
                     qkb, qkb, Vt, ctxb, 1);
  // 11. FFN1 (fused cWo)
  hipLaunchKernelGGL(gemm_bf16_kernel, dim3(4, 128), dim3(256), 0, stream,
                     s_b, 256, ctxb, 256, 256, cW1f,
                     cb1f, (const float*)nullptr, 1 << 30, 1.f, 1.f,
                     hbufb, 512, (u16*)nullptr, 0, 512);
  // 12. LN + GELU
  hipLaunchKernelGGL(ln_gelu_kernel, dim3(lng_blocks), dim3(256), 0, stream,
                     hbufb, c_g, c_be, hb2);
  // 13. W2 + residual -> fp32 output
  hipLaunchKernelGGL(gemm64_kernel, dim3(4, 256), dim3(256), 0, stream,
                     hb2, 512, cW2b, c_b2, s_b, 256,
                     outf, 256, (u16*)nullptr, 0, 512);
}